// Round 1
// baseline (21533.836 us; speedup 1.0000x reference)
//
#include <hip/hip_runtime.h>

// GRU B=64, T=512, IN=128, H=512, L=2, OUT=1 (fp32 in/out).
// R7: parallel validity-retry + 2-barrier step + register h_prev.
//   - fixN: one combined spin loop per staging phase; all invalid chunks'
//     agent loads issued back-to-back (1 MALL RTT covers everything) instead
//     of 4 serialized fix4 spins (up to 4 RTTs on the recurrence path).
//   - L0 speculative h loads issued BEFORE the X pack_split VALU work.
//   - h_prev carried in a register by the 256 gate threads (same (b,c) every
//     step), gates store tagged u32 directly -> hout buffer and the 3rd
//     __syncthreads are gone; waves 4-7 run ahead into step t+1 staging.
//   - make_afrag hi/lo split via v_perm_b32 (1 op instead of 6 per word).
//   - P partials stride PR=20: write banks = 16q+20r4+n mod 32 -> exactly
//     2 lanes/bank (free) vs 4-way at PR=17.
//   Everything else (flagless tagged-data sync, 0xAA poison, BIG/ring ws,
//   grid 256x512, K-split GEMM with register-resident split-bf16 weights)
//   unchanged from R6.

constexpr int Bb = 64, Tt = 512, DIN = 128, Hh = 512;
constexpr int BH = Bb * Hh;
constexpr int S0 = 644;    // LDS A-row stride (u32), layer0: 128 x + 512 h + 4 pad
constexpr int S1 = 1028;   // layer1: 512 h0 + 512 h1 + 4 pad
constexpr int PR = 20;     // partials row stride: conflict-free writes

typedef float  f32x4  __attribute__((ext_vector_type(4)));
typedef short  bf16x8 __attribute__((ext_vector_type(8)));
typedef int    i32x4  __attribute__((ext_vector_type(4)));
typedef unsigned long long u64;

#define MFMA16 __builtin_amdgcn_mfma_f32_16x16x32_bf16

__device__ __forceinline__ unsigned rne_bf16(unsigned xb){
    return (xb + 0x7FFFu + ((xb >> 16) & 1u)) >> 16;
}
__device__ __forceinline__ unsigned pack_split(float x){
    unsigned hb = rne_bf16(__float_as_uint(x));
    float hf = __uint_as_float(hb << 16);
    unsigned lb = rne_bf16(__float_as_uint(x - hf));
    return (hb << 16) | lb;
}
__device__ __forceinline__ float unpack_f32(unsigned u){
    return __uint_as_float(u & 0xFFFF0000u) + __uint_as_float(u << 16);
}

union FragU { unsigned w[4]; bf16x8 v; };

__device__ __forceinline__ void make_wfrag(const float* p, bf16x8& wh, bf16x8& wl){
    FragU hi, lo;
#pragma unroll
    for (int i = 0; i < 4; ++i){
        unsigned pa = pack_split(p[2*i]), pb = pack_split(p[2*i+1]);
        hi.w[i] = (pa >> 16) | (pb & 0xFFFF0000u);
        lo.w[i] = (pa & 0xFFFFu) | (pb << 16);
    }
    wh = hi.v; wl = lo.v;
}
// hi word = [b3,b2,a3,a2], lo word = [b1,b0,a1,a0] -- one v_perm_b32 each.
__device__ __forceinline__ void make_afrag(const unsigned* u, bf16x8& ah, bf16x8& al){
    FragU hi, lo;
#pragma unroll
    for (int i = 0; i < 4; ++i){
        unsigned a = u[2*i], b = u[2*i+1];
        hi.w[i] = __builtin_amdgcn_perm(b, a, 0x07060302u);
        lo.w[i] = __builtin_amdgcn_perm(b, a, 0x05040100u);
    }
    ah = hi.v; al = lo.v;
}

__device__ __forceinline__ u64 ald64(const u64* p){
    return __hip_atomic_load(p, __ATOMIC_RELAXED, __HIP_MEMORY_SCOPE_AGENT);
}
__device__ __forceinline__ void ast32(unsigned* p, unsigned v){
    __hip_atomic_store(p, v, __ATOMIC_RELAXED, __HIP_MEMORY_SCOPE_AGENT);
}

// all 4 words must have bit0 == tag
__device__ __forceinline__ bool bad4(const i32x4& v, unsigned tag){
    unsigned x = ((unsigned)v[0] ^ tag) | ((unsigned)v[1] ^ tag)
               | ((unsigned)v[2] ^ tag) | ((unsigned)v[3] ^ tag);
    return (x & 1u) != 0u;
}
__device__ __forceinline__ bool bad64(u64 v, unsigned tag){
    return (((((unsigned)v) ^ tag) | (((unsigned)(v >> 32)) ^ tag)) & 1u) != 0u;
}

// Combined retry: issue ALL still-invalid chunks' agent loads back-to-back,
// then check -- one MALL round trip covers every bad chunk per iteration.
template<int N>
__device__ __forceinline__ void fixN(const unsigned* const (&p)[N],
                                     const unsigned (&tg)[N], i32x4 (&v)[N]){
    unsigned bad = 0;
#pragma unroll
    for (int i = 0; i < N; ++i) bad |= (unsigned)bad4(v[i], tg[i]) << i;
    while (__builtin_expect(bad != 0u, 0)){
        u64 A[N], B[N];
#pragma unroll
        for (int i = 0; i < N; ++i) if (bad & (1u << i)){
            A[i] = ald64((const u64*)p[i]);
            B[i] = ald64((const u64*)p[i] + 1);
        }
#pragma unroll
        for (int i = 0; i < N; ++i) if (bad & (1u << i)){
            i32x4 nv;
            nv[0] = (int)(unsigned)A[i]; nv[1] = (int)(unsigned)(A[i] >> 32);
            nv[2] = (int)(unsigned)B[i]; nv[3] = (int)(unsigned)(B[i] >> 32);
            v[i] = nv;
            if (!bad4(nv, tg[i])) bad &= ~(1u << i);
        }
        if (bad) __builtin_amdgcn_s_sleep(1);
    }
}

template<bool BIG>
__global__ __launch_bounds__(512, 1) void gru_main(
    const float* __restrict__ X,
    const float* __restrict__ Wih0, const float* __restrict__ Whh0,
    const float* __restrict__ bih0, const float* __restrict__ bhh0,
    const float* __restrict__ Wih1, const float* __restrict__ Whh1,
    const float* __restrict__ bih1, const float* __restrict__ bhh1,
    const float* __restrict__ fcW, const float* __restrict__ fcb,
    float* __restrict__ out,
    unsigned* hseq0, unsigned* hseq1)
{
    // Kill stale clean L1/L2 lines left from the previous graph replay.
    __builtin_amdgcn_fence(__ATOMIC_ACQUIRE, "agent");

    __shared__ unsigned Alds[16 * S1];
    __shared__ float P[8][3][16 * PR];

    const int tid  = threadIdx.x;
    const int lane = tid & 63;
    const int w    = tid >> 6;
    const bool isL1 = blockIdx.x >= 128;
    const int lb = isL1 ? (int)blockIdx.x - 128 : (int)blockIdx.x;
    const int m  = lb >> 5;                // batch tile 0..3
    const int cb = lb & 31;                // col-block 0..31
    const int c0 = cb * 16;
    const int STR  = isL1 ? S1 : S0;

    const bool active = isL1 || (w < 5);   // layer0 K=640 -> 5 waves x 128

    // ---- register-resident weight fragments (hi/lo split-bf16) ----
    bf16x8 whi[4][3], wlo[4][3];
    if (active){
        const int n = lane & 15;
#pragma unroll
        for (int ks = 0; ks < 4; ++ks){
            int kq = w * 128 + ks * 32 + (lane >> 4) * 8;
            const float* src; long kloc, rowlen;
            if (isL1){
                if (kq < 512){ src = Wih1; kloc = kq; } else { src = Whh1; kloc = kq - 512; }
                rowlen = 512;
            } else {
                if (kq < 128){ src = Wih0; kloc = kq; rowlen = 128; }
                else         { src = Whh0; kloc = kq - 128; rowlen = 512; }
            }
#pragma unroll
            for (int g = 0; g < 3; ++g){
                long row = (long)g * Hh + c0 + n;
                make_wfrag(src + row * rowlen + kloc, whi[ks][g], wlo[ks][g]);
            }
        }
    }
    // ---- biases for epilogue ----
    float Br = 0.f, Bz = 0.f, Bin = 0.f, Bhn = 0.f;
    if (tid < 256){
        int c = c0 + (tid & 15);
        const float* bi = isL1 ? bih1 : bih0;
        const float* bh = isL1 ? bhh1 : bhh0;
        Br  = bi[c] + bh[c];
        Bz  = bi[Hh + c] + bh[Hh + c];
        Bin = bi[2*Hh + c];
        Bhn = bh[2*Hh + c];
    }

    float hp = 0.f;                        // register-carried h_prev (gate threads)

    for (int t = 0; t < Tt; ++t){
        // ---- staging: speculative loads + ONE combined validity fix-up ----
        if (isL1){
            const unsigned* s0 = hseq0 + ((long)t * Bb + m*16) * (long)Hh;
            long r1 = BIG ? (long)(t-1) * BH : (long)((t-1) & 1) * BH;
            const unsigned* s1 = hseq1 + r1 + (long)(m*16) * Hh;
            unsigned tag1 = BIG ? 1u : (1u - (((unsigned)(t-1) >> 1) & 1u));
            if (t > 0){
                const unsigned* aP[8]; unsigned tg[8]; i32x4 vv[8];
#pragma unroll
                for (int it = 0; it < 4; ++it){
                    int j = it*512 + tid; int row = j >> 7, col = (j & 127) * 4;
                    aP[it] = s0 + (long)row * Hh + col;
                    vv[it] = *(const i32x4*)aP[it];
                    tg[it] = 1u;
                }
#pragma unroll
                for (int it = 0; it < 4; ++it){
                    int j = it*512 + tid; int row = j >> 7, col = (j & 127) * 4;
                    aP[4+it] = s1 + (long)row * Hh + col;
                    vv[4+it] = *(const i32x4*)aP[4+it];
                    tg[4+it] = tag1;
                }
                fixN<8>(aP, tg, vv);
#pragma unroll
                for (int it = 0; it < 4; ++it){
                    int j = it*512 + tid; int row = j >> 7, col = (j & 127) * 4;
                    *(i32x4*)(Alds + row * S1 + col) = vv[it];
                    *(i32x4*)(Alds + row * S1 + 512 + col) = vv[4+it];
                }
            } else {
                const unsigned* aP[4]; unsigned tg[4]; i32x4 vv[4];
#pragma unroll
                for (int it = 0; it < 4; ++it){
                    int j = it*512 + tid; int row = j >> 7, col = (j & 127) * 4;
                    aP[it] = s0 + (long)row * Hh + col;
                    vv[it] = *(const i32x4*)aP[it];
                    tg[it] = 1u;
                }
                fixN<4>(aP, tg, vv);
#pragma unroll
                for (int it = 0; it < 4; ++it){
                    int j = it*512 + tid; int row = j >> 7, col = (j & 127) * 4;
                    *(i32x4*)(Alds + row * S1 + col) = vv[it];
                    *(i32x4*)(Alds + row * S1 + 512 + col) = i32x4{0,0,0,0};
                }
            }
        } else {
            // issue speculative h loads FIRST so pack_split VALU hides latency
            const unsigned* aP[4]; unsigned tg[4]; i32x4 vv[4];
            if (t > 0){
                const unsigned* s0 = hseq0 + ((long)(t-1) * Bb + m*16) * (long)Hh;
#pragma unroll
                for (int it = 0; it < 4; ++it){
                    int j = it*512 + tid; int row = j >> 7, col = (j & 127) * 4;
                    aP[it] = s0 + (long)row * Hh + col;
                    vv[it] = *(const i32x4*)aP[it];
                    tg[it] = 1u;
                }
            }
            // X[t] fp32 (cached input) -> pack on the fly
            {
                int row = tid >> 5, c4 = (tid & 31) * 4;
                f32x4 xv = *(const f32x4*)(X + ((long)(m*16 + row) * Tt + t) * DIN + c4);
                i32x4 pv;
                pv[0] = (int)pack_split(xv[0]);
                pv[1] = (int)pack_split(xv[1]);
                pv[2] = (int)pack_split(xv[2]);
                pv[3] = (int)pack_split(xv[3]);
                *(i32x4*)(Alds + row * S0 + c4) = pv;
            }
            if (t > 0){
                fixN<4>(aP, tg, vv);
#pragma unroll
                for (int it = 0; it < 4; ++it){
                    int j = it*512 + tid; int row = j >> 7, col = (j & 127) * 4;
                    *(i32x4*)(Alds + row * S0 + 128 + col) = vv[it];
                }
            } else {
#pragma unroll
                for (int it = 0; it < 8; ++it){
                    int j = it*512 + tid;
                    *(u64*)(Alds + (j >> 8) * S0 + 128 + (j & 255) * 2) = 0ULL;
                }
            }
        }
        __syncthreads();

        // ---- MFMA: this wave's K-slice, tiles {r, z, nx-or-nh} ----
        if (active){
            f32x4 acc0 = {0.f,0.f,0.f,0.f}, acc1 = acc0, acc2 = acc0;
            const unsigned* arow = Alds + (lane & 15) * STR + w * 128 + (lane >> 4) * 8;
#pragma unroll
            for (int ks = 0; ks < 4; ++ks){
                unsigned uu[8];
                *(i32x4*)&uu[0] = *(const i32x4*)(arow + ks*32);
                *(i32x4*)&uu[4] = *(const i32x4*)(arow + ks*32 + 4);
                bf16x8 ah, al; make_afrag(uu, ah, al);
                acc0 = MFMA16(ah, whi[ks][0], acc0, 0,0,0);
                acc0 = MFMA16(ah, wlo[ks][0], acc0, 0,0,0);
                acc0 = MFMA16(al, whi[ks][0], acc0, 0,0,0);
                acc1 = MFMA16(ah, whi[ks][1], acc1, 0,0,0);
                acc1 = MFMA16(ah, wlo[ks][1], acc1, 0,0,0);
                acc1 = MFMA16(al, whi[ks][1], acc1, 0,0,0);
                acc2 = MFMA16(ah, whi[ks][2], acc2, 0,0,0);
                acc2 = MFMA16(ah, wlo[ks][2], acc2, 0,0,0);
                acc2 = MFMA16(al, whi[ks][2], acc2, 0,0,0);
            }
            int q = lane >> 4, n = lane & 15;
#pragma unroll
            for (int r4 = 0; r4 < 4; ++r4){
                int idx = (q*4 + r4)*PR + n;
                P[w][0][idx] = acc0[r4];
                P[w][1][idx] = acc1[r4];
                P[w][2][idx] = acc2[r4];
            }
        }
        __syncthreads();

        // ---- reduce partials + gates -> direct tagged u32 agent store ----
        // (h_prev is register-carried; no hout buffer, no 3rd barrier:
        //  waves 4-7 sail into step t+1 staging while gates finish)
        unsigned wtag = isL1 ? (BIG ? 1u : (1u - (((unsigned)t >> 1) & 1u))) : 1u;
        if (tid < 256){
            int bm = tid >> 4, n = tid & 15;
            int idx = bm * PR + n;
            float sr, sz, snx, snh;
            if (isL1){
                sr  = P[0][0][idx]+P[1][0][idx]+P[2][0][idx]+P[3][0][idx]
                    + P[4][0][idx]+P[5][0][idx]+P[6][0][idx]+P[7][0][idx];
                sz  = P[0][1][idx]+P[1][1][idx]+P[2][1][idx]+P[3][1][idx]
                    + P[4][1][idx]+P[5][1][idx]+P[6][1][idx]+P[7][1][idx];
                snx = P[0][2][idx]+P[1][2][idx]+P[2][2][idx]+P[3][2][idx];
                snh = P[4][2][idx]+P[5][2][idx]+P[6][2][idx]+P[7][2][idx];
            } else {
                sr  = P[0][0][idx]+P[1][0][idx]+P[2][0][idx]+P[3][0][idx]+P[4][0][idx];
                sz  = P[0][1][idx]+P[1][1][idx]+P[2][1][idx]+P[3][1][idx]+P[4][1][idx];
                snx = P[0][2][idx];
                snh = P[1][2][idx]+P[2][2][idx]+P[3][2][idx]+P[4][2][idx];
            }
            float r  = 1.f/(1.f + __expf(-(sr + Br)));
            float z  = 1.f/(1.f + __expf(-(sz + Bz)));
            float ee = __expf(2.f*(snx + Bin + r*(snh + Bhn)));
            float nn = 1.f - 2.f/(ee + 1.f);
            float hnew = (1.f - z)*nn + z*hp;
            hp = hnew;
            unsigned pv = (pack_split(hnew) & ~1u) | wtag;
            unsigned* base = isL1
                ? hseq1 + (BIG ? (long)t * BH : (long)(t & 1) * BH)
                : hseq0 + (long)t * BH;
            ast32(base + (long)(m*16 + bm) * Hh + c0 + n, pv);
        }
        // no barrier: next staging writes Alds only (disjoint from P reads);
        // sync1 of t+1 orders epilogue P-reads vs next MFMA P-writes.
    }

    // ---- FC epilogue: one layer1 block per m, parallel validated reads ----
    if (isL1 && cb == 31){
        unsigned ftag = BIG ? 1u : (1u - (((unsigned)(Tt-1) >> 1) & 1u));
        const unsigned* hb = hseq1 + (BIG ? (long)(Tt-1) * BH : (long)((Tt-1) & 1) * BH);
        int half = lane >> 5, l5 = lane & 31;
        int b = m*16 + w*2 + half;
        const u64* hrow = (const u64*)(hb + (long)b * Hh);
        u64 v[8];
#pragma unroll
        for (int i = 0; i < 8; ++i) v[i] = ald64(hrow + l5 + 32*i);
        unsigned bad = 0;
#pragma unroll
        for (int i = 0; i < 8; ++i) bad |= (unsigned)bad64(v[i], ftag) << i;
        while (__builtin_expect(bad != 0u, 0)){
#pragma unroll
            for (int i = 0; i < 8; ++i) if (bad & (1u << i)) v[i] = ald64(hrow + l5 + 32*i);
#pragma unroll
            for (int i = 0; i < 8; ++i) if (bad & (1u << i)){
                if (!bad64(v[i], ftag)) bad &= ~(1u << i);
            }
            if (bad) __builtin_amdgcn_s_sleep(1);
        }
        float p = 0.f;
#pragma unroll
        for (int i = 0; i < 8; ++i){
            int k = l5 + 32*i;
            p += unpack_f32((unsigned)v[i]) * fcW[2*k]
               + unpack_f32((unsigned)(v[i] >> 32)) * fcW[2*k+1];
        }
#pragma unroll
        for (int off = 16; off > 0; off >>= 1) p += __shfl_xor(p, off);
        if (l5 == 0) out[b] = p + fcb[0];
    }
}

extern "C" void kernel_launch(void* const* d_in, const int* in_sizes, int n_in,
                              void* d_out, int out_size, void* d_ws, size_t ws_size,
                              hipStream_t stream) {
    const float* X    = (const float*)d_in[0];
    const float* Wih0 = (const float*)d_in[1];
    const float* Whh0 = (const float*)d_in[2];
    const float* bih0 = (const float*)d_in[3];
    const float* bhh0 = (const float*)d_in[4];
    const float* Wih1 = (const float*)d_in[5];
    const float* Whh1 = (const float*)d_in[6];
    const float* bih1 = (const float*)d_in[7];
    const float* bhh1 = (const float*)d_in[8];
    const float* fcW  = (const float*)d_in[9];
    const float* fcb  = (const float*)d_in[10];
    float* out = (float*)d_out;

    // ws: hseq0 64 MiB | hseq1 64 MiB (BIG) or 256 KiB ring. No flags, no memset:
    // harness poisons ws to 0xAA (bit0=0 = invalid) before every launch.
    unsigned* hseq0 = (unsigned*)d_ws;
    unsigned* hseq1 = hseq0 + (long)Tt * BH;
    size_t need_big = (size_t)2 * Tt * BH * 4;    // 128 MiB
    bool big = ws_size >= need_big;

    if (big)
        gru_main<true><<<256, 512, 0, stream>>>(X, Wih0, Whh0, bih0, bhh0,
                                                Wih1, Whh1, bih1, bhh1, fcW, fcb,
                                                out, hseq0, hseq1);
    else
        gru_main<false><<<256, 512, 0, stream>>>(X, Wih0, Whh0, bih0, bhh0,
                                                 Wih1, Whh1, bih1, bhh1, fcW, fcb,
                                                 out, hseq0, hseq1);
}

// Round 3
// 19215.562 us; speedup vs baseline: 1.1206x; 1.1206x over previous
//
#include <hip/hip_runtime.h>

// GRU B=64, T=512, IN=128, H=512, L=2, OUT=1 (fp32 in/out).
// R8 (resubmit; R2 bench was a GPUAcquisitionTimeout, kernel never ran):
// R6 sync skeleton restored (3 barriers, hout, u64 stores, lockstep)
//     + structure-preserving grafts from R7:
//   - fixN: combined parallel validity-retry (all invalid chunks' agent
//     loads issued back-to-back; 1 MALL RTT covers everything) instead of
//     serialized per-chunk fix4 spins.
//   - make_afrag hi/lo split via v_perm_b32 (1 op instead of 6 per word).
//   - P partials stride PR=20: write banks 2 lanes/bank (free) vs 4-way.
//   - h_prev carried in a register by gate threads (same (b,c) every step).
//   - L0 speculative h loads issued BEFORE the X pack_split VALU work.
//   - FC epilogue uses batched parallel validated reads.
//   R7 lesson (WRITE_SIZE 134MB->42GB, dur 12x): removing the 3rd barrier
//   desyncs blocks -> agent-load spin storm saturates fabric. Lockstep is
//   load-bearing; do NOT let waves run ahead of the tagged stores.

constexpr int Bb = 64, Tt = 512, DIN = 128, Hh = 512;
constexpr int BH = Bb * Hh;
constexpr int S0 = 644;    // LDS A-row stride (u32), layer0: 128 x + 512 h + 4 pad
constexpr int S1 = 1028;   // layer1: 512 h0 + 512 h1 + 4 pad
constexpr int PR = 20;     // partials row stride: conflict-free writes

typedef float  f32x4  __attribute__((ext_vector_type(4)));
typedef short  bf16x8 __attribute__((ext_vector_type(8)));
typedef int    i32x4  __attribute__((ext_vector_type(4)));
typedef unsigned long long u64;

#define MFMA16 __builtin_amdgcn_mfma_f32_16x16x32_bf16

__device__ __forceinline__ unsigned rne_bf16(unsigned xb){
    return (xb + 0x7FFFu + ((xb >> 16) & 1u)) >> 16;
}
__device__ __forceinline__ unsigned pack_split(float x){
    unsigned hb = rne_bf16(__float_as_uint(x));
    float hf = __uint_as_float(hb << 16);
    unsigned lb = rne_bf16(__float_as_uint(x - hf));
    return (hb << 16) | lb;
}
__device__ __forceinline__ float unpack_f32(unsigned u){
    return __uint_as_float(u & 0xFFFF0000u) + __uint_as_float(u << 16);
}

union FragU { unsigned w[4]; bf16x8 v; };

__device__ __forceinline__ void make_wfrag(const float* p, bf16x8& wh, bf16x8& wl){
    FragU hi, lo;
#pragma unroll
    for (int i = 0; i < 4; ++i){
        unsigned pa = pack_split(p[2*i]), pb = pack_split(p[2*i+1]);
        hi.w[i] = (pa >> 16) | (pb & 0xFFFF0000u);
        lo.w[i] = (pa & 0xFFFFu) | (pb << 16);
    }
    wh = hi.v; wl = lo.v;
}
// hi word = [b3,b2,a3,a2], lo word = [b1,b0,a1,a0] -- one v_perm_b32 each.
__device__ __forceinline__ void make_afrag(const unsigned* u, bf16x8& ah, bf16x8& al){
    FragU hi, lo;
#pragma unroll
    for (int i = 0; i < 4; ++i){
        unsigned a = u[2*i], b = u[2*i+1];
        hi.w[i] = __builtin_amdgcn_perm(b, a, 0x07060302u);
        lo.w[i] = __builtin_amdgcn_perm(b, a, 0x05040100u);
    }
    ah = hi.v; al = lo.v;
}

__device__ __forceinline__ u64 ald64(const u64* p){
    return __hip_atomic_load(p, __ATOMIC_RELAXED, __HIP_MEMORY_SCOPE_AGENT);
}
__device__ __forceinline__ void ast64(u64* p, u64 v){
    __hip_atomic_store(p, v, __ATOMIC_RELAXED, __HIP_MEMORY_SCOPE_AGENT);
}

// all 4 words must have bit0 == tag
__device__ __forceinline__ bool bad4(const i32x4& v, unsigned tag){
    unsigned x = ((unsigned)v[0] ^ tag) | ((unsigned)v[1] ^ tag)
               | ((unsigned)v[2] ^ tag) | ((unsigned)v[3] ^ tag);
    return (x & 1u) != 0u;
}
__device__ __forceinline__ bool bad64(u64 v, unsigned tag){
    return (((((unsigned)v) ^ tag) | (((unsigned)(v >> 32)) ^ tag)) & 1u) != 0u;
}

// Combined retry: issue ALL still-invalid chunks' agent loads back-to-back,
// then check -- one MALL round trip covers every bad chunk per iteration.
template<int N>
__device__ __forceinline__ void fixN(const unsigned* const (&p)[N],
                                     const unsigned (&tg)[N], i32x4 (&v)[N]){
    unsigned bad = 0;
#pragma unroll
    for (int i = 0; i < N; ++i) bad |= (unsigned)bad4(v[i], tg[i]) << i;
    while (__builtin_expect(bad != 0u, 0)){
        u64 A[N], B[N];
#pragma unroll
        for (int i = 0; i < N; ++i) if (bad & (1u << i)){
            A[i] = ald64((const u64*)p[i]);
            B[i] = ald64((const u64*)p[i] + 1);
        }
#pragma unroll
        for (int i = 0; i < N; ++i) if (bad & (1u << i)){
            i32x4 nv;
            nv[0] = (int)(unsigned)A[i]; nv[1] = (int)(unsigned)(A[i] >> 32);
            nv[2] = (int)(unsigned)B[i]; nv[3] = (int)(unsigned)(B[i] >> 32);
            v[i] = nv;
            if (!bad4(nv, tg[i])) bad &= ~(1u << i);
        }
        if (bad) __builtin_amdgcn_s_sleep(1);
    }
}

template<bool BIG>
__global__ __launch_bounds__(512, 1) void gru_main(
    const float* __restrict__ X,
    const float* __restrict__ Wih0, const float* __restrict__ Whh0,
    const float* __restrict__ bih0, const float* __restrict__ bhh0,
    const float* __restrict__ Wih1, const float* __restrict__ Whh1,
    const float* __restrict__ bih1, const float* __restrict__ bhh1,
    const float* __restrict__ fcW, const float* __restrict__ fcb,
    float* __restrict__ out,
    unsigned* hseq0, unsigned* hseq1)
{
    // Kill stale clean L1/L2 lines left from the previous graph replay.
    __builtin_amdgcn_fence(__ATOMIC_ACQUIRE, "agent");

    __shared__ unsigned Alds[16 * S1];
    __shared__ float P[8][3][16 * PR];
    __shared__ unsigned hout[256];

    const int tid  = threadIdx.x;
    const int lane = tid & 63;
    const int w    = tid >> 6;
    const bool isL1 = blockIdx.x >= 128;
    const int lb = isL1 ? (int)blockIdx.x - 128 : (int)blockIdx.x;
    const int m  = lb >> 5;                // batch tile 0..3
    const int cb = lb & 31;                // col-block 0..31
    const int c0 = cb * 16;
    const int STR  = isL1 ? S1 : S0;

    const bool active = isL1 || (w < 5);   // layer0 K=640 -> 5 waves x 128

    // ---- register-resident weight fragments (hi/lo split-bf16) ----
    bf16x8 whi[4][3], wlo[4][3];
    if (active){
        const int n = lane & 15;
#pragma unroll
        for (int ks = 0; ks < 4; ++ks){
            int kq = w * 128 + ks * 32 + (lane >> 4) * 8;
            const float* src; long kloc, rowlen;
            if (isL1){
                if (kq < 512){ src = Wih1; kloc = kq; } else { src = Whh1; kloc = kq - 512; }
                rowlen = 512;
            } else {
                if (kq < 128){ src = Wih0; kloc = kq; rowlen = 128; }
                else         { src = Whh0; kloc = kq - 128; rowlen = 512; }
            }
#pragma unroll
            for (int g = 0; g < 3; ++g){
                long row = (long)g * Hh + c0 + n;
                make_wfrag(src + row * rowlen + kloc, whi[ks][g], wlo[ks][g]);
            }
        }
    }
    // ---- biases for epilogue ----
    float Br = 0.f, Bz = 0.f, Bin = 0.f, Bhn = 0.f;
    if (tid < 256){
        int c = c0 + (tid & 15);
        const float* bi = isL1 ? bih1 : bih0;
        const float* bh = isL1 ? bhh1 : bhh0;
        Br  = bi[c] + bh[c];
        Bz  = bi[Hh + c] + bh[Hh + c];
        Bin = bi[2*Hh + c];
        Bhn = bh[2*Hh + c];
    }

    float hp = 0.f;                        // register-carried h_prev (gate threads)

    for (int t = 0; t < Tt; ++t){
        // ---- staging: speculative loads + ONE combined validity fix-up ----
        if (isL1){
            const unsigned* s0 = hseq0 + ((long)t * Bb + m*16) * (long)Hh;
            long r1 = BIG ? (long)(t-1) * BH : (long)((t-1) & 1) * BH;
            const unsigned* s1 = hseq1 + r1 + (long)(m*16) * Hh;
            unsigned tag1 = BIG ? 1u : (1u - (((unsigned)(t-1) >> 1) & 1u));
            if (t > 0){
                const unsigned* aP[8]; unsigned tg[8]; i32x4 vv[8];
#pragma unroll
                for (int it = 0; it < 4; ++it){
                    int j = it*512 + tid; int row = j >> 7, col = (j & 127) * 4;
                    aP[it] = s0 + (long)row * Hh + col;
                    vv[it] = *(const i32x4*)aP[it];
                    tg[it] = 1u;
                }
#pragma unroll
                for (int it = 0; it < 4; ++it){
                    int j = it*512 + tid; int row = j >> 7, col = (j & 127) * 4;
                    aP[4+it] = s1 + (long)row * Hh + col;
                    vv[4+it] = *(const i32x4*)aP[4+it];
                    tg[4+it] = tag1;
                }
                fixN<8>(aP, tg, vv);
#pragma unroll
                for (int it = 0; it < 4; ++it){
                    int j = it*512 + tid; int row = j >> 7, col = (j & 127) * 4;
                    *(i32x4*)(Alds + row * S1 + col) = vv[it];
                    *(i32x4*)(Alds + row * S1 + 512 + col) = vv[4+it];
                }
            } else {
                const unsigned* aP[4]; unsigned tg[4]; i32x4 vv[4];
#pragma unroll
                for (int it = 0; it < 4; ++it){
                    int j = it*512 + tid; int row = j >> 7, col = (j & 127) * 4;
                    aP[it] = s0 + (long)row * Hh + col;
                    vv[it] = *(const i32x4*)aP[it];
                    tg[it] = 1u;
                }
                fixN<4>(aP, tg, vv);
#pragma unroll
                for (int it = 0; it < 4; ++it){
                    int j = it*512 + tid; int row = j >> 7, col = (j & 127) * 4;
                    *(i32x4*)(Alds + row * S1 + col) = vv[it];
                    *(i32x4*)(Alds + row * S1 + 512 + col) = i32x4{0,0,0,0};
                }
            }
        } else {
            // issue speculative h loads FIRST so pack_split VALU hides latency
            const unsigned* aP[4]; unsigned tg[4]; i32x4 vv[4];
            if (t > 0){
                const unsigned* s0 = hseq0 + ((long)(t-1) * Bb + m*16) * (long)Hh;
#pragma unroll
                for (int it = 0; it < 4; ++it){
                    int j = it*512 + tid; int row = j >> 7, col = (j & 127) * 4;
                    aP[it] = s0 + (long)row * Hh + col;
                    vv[it] = *(const i32x4*)aP[it];
                    tg[it] = 1u;
                }
            }
            // X[t] fp32 (cached input) -> pack on the fly
            {
                int row = tid >> 5, c4 = (tid & 31) * 4;
                f32x4 xv = *(const f32x4*)(X + ((long)(m*16 + row) * Tt + t) * DIN + c4);
                i32x4 pv;
                pv[0] = (int)pack_split(xv[0]);
                pv[1] = (int)pack_split(xv[1]);
                pv[2] = (int)pack_split(xv[2]);
                pv[3] = (int)pack_split(xv[3]);
                *(i32x4*)(Alds + row * S0 + c4) = pv;
            }
            if (t > 0){
                fixN<4>(aP, tg, vv);
#pragma unroll
                for (int it = 0; it < 4; ++it){
                    int j = it*512 + tid; int row = j >> 7, col = (j & 127) * 4;
                    *(i32x4*)(Alds + row * S0 + 128 + col) = vv[it];
                }
            } else {
#pragma unroll
                for (int it = 0; it < 8; ++it){
                    int j = it*512 + tid;
                    *(u64*)(Alds + (j >> 8) * S0 + 128 + (j & 255) * 2) = 0ULL;
                }
            }
        }
        __syncthreads();

        // ---- MFMA: this wave's K-slice, tiles {r, z, nx-or-nh} ----
        if (active){
            f32x4 acc0 = {0.f,0.f,0.f,0.f}, acc1 = acc0, acc2 = acc0;
            const unsigned* arow = Alds + (lane & 15) * STR + w * 128 + (lane >> 4) * 8;
#pragma unroll
            for (int ks = 0; ks < 4; ++ks){
                unsigned uu[8];
                *(i32x4*)&uu[0] = *(const i32x4*)(arow + ks*32);
                *(i32x4*)&uu[4] = *(const i32x4*)(arow + ks*32 + 4);
                bf16x8 ah, al; make_afrag(uu, ah, al);
                acc0 = MFMA16(ah, whi[ks][0], acc0, 0,0,0);
                acc0 = MFMA16(ah, wlo[ks][0], acc0, 0,0,0);
                acc0 = MFMA16(al, whi[ks][0], acc0, 0,0,0);
                acc1 = MFMA16(ah, whi[ks][1], acc1, 0,0,0);
                acc1 = MFMA16(ah, wlo[ks][1], acc1, 0,0,0);
                acc1 = MFMA16(al, whi[ks][1], acc1, 0,0,0);
                acc2 = MFMA16(ah, whi[ks][2], acc2, 0,0,0);
                acc2 = MFMA16(ah, wlo[ks][2], acc2, 0,0,0);
                acc2 = MFMA16(al, whi[ks][2], acc2, 0,0,0);
            }
            int q = lane >> 4, n = lane & 15;
#pragma unroll
            for (int r4 = 0; r4 < 4; ++r4){
                int idx = (q*4 + r4)*PR + n;
                P[w][0][idx] = acc0[r4];
                P[w][1][idx] = acc1[r4];
                P[w][2][idx] = acc2[r4];
            }
        }
        __syncthreads();

        // ---- reduce partials + gates -> tagged packed h into LDS ----
        unsigned wtag = isL1 ? (BIG ? 1u : (1u - (((unsigned)t >> 1) & 1u))) : 1u;
        if (tid < 256){
            int bm = tid >> 4, n = tid & 15;
            int idx = bm * PR + n;
            float sr, sz, snx, snh;
            if (isL1){
                sr  = P[0][0][idx]+P[1][0][idx]+P[2][0][idx]+P[3][0][idx]
                    + P[4][0][idx]+P[5][0][idx]+P[6][0][idx]+P[7][0][idx];
                sz  = P[0][1][idx]+P[1][1][idx]+P[2][1][idx]+P[3][1][idx]
                    + P[4][1][idx]+P[5][1][idx]+P[6][1][idx]+P[7][1][idx];
                snx = P[0][2][idx]+P[1][2][idx]+P[2][2][idx]+P[3][2][idx];
                snh = P[4][2][idx]+P[5][2][idx]+P[6][2][idx]+P[7][2][idx];
            } else {
                sr  = P[0][0][idx]+P[1][0][idx]+P[2][0][idx]+P[3][0][idx]+P[4][0][idx];
                sz  = P[0][1][idx]+P[1][1][idx]+P[2][1][idx]+P[3][1][idx]+P[4][1][idx];
                snx = P[0][2][idx];
                snh = P[1][2][idx]+P[2][2][idx]+P[3][2][idx]+P[4][2][idx];
            }
            float r  = 1.f/(1.f + __expf(-(sr + Br)));
            float z  = 1.f/(1.f + __expf(-(sz + Bz)));
            float ee = __expf(2.f*(snx + Bin + r*(snh + Bhn)));
            float nn = 1.f - 2.f/(ee + 1.f);
            float hnew = (1.f - z)*nn + z*hp;
            hp = hnew;
            hout[tid] = (pack_split(hnew) & ~1u) | wtag;   // hout[bm*16 + n]
        }
        __syncthreads();

        // ---- agent u64 stores; NO ack wait, NO flag — sail into t+1 ----
        if (tid < 128){
            int bm = tid >> 3, k = (tid & 7) * 2;
            u64 v = (u64)hout[bm*16 + k] | ((u64)hout[bm*16 + k + 1] << 32);
            unsigned* base = isL1
                ? hseq1 + (BIG ? (long)t * BH : (long)(t & 1) * BH)
                : hseq0 + (long)t * BH;
            ast64((u64*)(base + (long)(m*16 + bm) * Hh + c0 + k), v);
        }
    }

    // ---- FC epilogue: one layer1 block per m, parallel validated reads ----
    if (isL1 && cb == 31){
        unsigned ftag = BIG ? 1u : (1u - (((unsigned)(Tt-1) >> 1) & 1u));
        const unsigned* hb = hseq1 + (BIG ? (long)(Tt-1) * BH : (long)((Tt-1) & 1) * BH);
        int half = lane >> 5, l5 = lane & 31;
        int b = m*16 + w*2 + half;
        const u64* hrow = (const u64*)(hb + (long)b * Hh);
        u64 v[8];
#pragma unroll
        for (int i = 0; i < 8; ++i) v[i] = ald64(hrow + l5 + 32*i);
        unsigned bad = 0;
#pragma unroll
        for (int i = 0; i < 8; ++i) bad |= (unsigned)bad64(v[i], ftag) << i;
        while (__builtin_expect(bad != 0u, 0)){
#pragma unroll
            for (int i = 0; i < 8; ++i) if (bad & (1u << i)) v[i] = ald64(hrow + l5 + 32*i);
#pragma unroll
            for (int i = 0; i < 8; ++i) if (bad & (1u << i)){
                if (!bad64(v[i], ftag)) bad &= ~(1u << i);
            }
            if (bad) __builtin_amdgcn_s_sleep(1);
        }
        float p = 0.f;
#pragma unroll
        for (int i = 0; i < 8; ++i){
            int k = l5 + 32*i;
            p += unpack_f32((unsigned)v[i]) * fcW[2*k]
               + unpack_f32((unsigned)(v[i] >> 32)) * fcW[2*k+1];
        }
#pragma unroll
        for (int off = 16; off > 0; off >>= 1) p += __shfl_xor(p, off);
        if (l5 == 0) out[b] = p + fcb[0];
    }
}

extern "C" void kernel_launch(void* const* d_in, const int* in_sizes, int n_in,
                              void* d_out, int out_size, void* d_ws, size_t ws_size,
                              hipStream_t stream) {
    const float* X    = (const float*)d_in[0];
    const float* Wih0 = (const float*)d_in[1];
    const float* Whh0 = (const float*)d_in[2];
    const float* bih0 = (const float*)d_in[3];
    const float* bhh0 = (const float*)d_in[4];
    const float* Wih1 = (const float*)d_in[5];
    const float* Whh1 = (const float*)d_in[6];
    const float* bih1 = (const float*)d_in[7];
    const float* bhh1 = (const float*)d_in[8];
    const float* fcW  = (const float*)d_in[9];
    const float* fcb  = (const float*)d_in[10];
    float* out = (float*)d_out;

    // ws: hseq0 64 MiB | hseq1 64 MiB (BIG) or 256 KiB ring. No flags, no memset:
    // harness poisons ws to 0xAA (bit0=0 = invalid) before every launch.
    unsigned* hseq0 = (unsigned*)d_ws;
    unsigned* hseq1 = hseq0 + (long)Tt * BH;
    size_t need_big = (size_t)2 * Tt * BH * 4;    // 128 MiB
    bool big = ws_size >= need_big;

    if (big)
        gru_main<true><<<256, 512, 0, stream>>>(X, Wih0, Whh0, bih0, bhh0,
                                                Wih1, Whh1, bih1, bhh1, fcW, fcb,
                                                out, hseq0, hseq1);
    else
        gru_main<false><<<256, 512, 0, stream>>>(X, Wih0, Whh0, bih0, bhh0,
                                                 Wih1, Whh1, bih1, bhh1, fcW, fcb,
                                                 out, hseq0, hseq1);
}

// Round 4
// 1722.765 us; speedup vs baseline: 12.4996x; 11.1539x over previous
//
#include <hip/hip_runtime.h>

// GRU B=64, T=512, IN=128, H=512, L=2, OUT=1 (fp32 in/out).
// R9: R6 verbatim (sync path byte-identical: serialized fix4 retry, R6 load
// ordering, h_prev from Alds, hout + 3 barriers, u64 stores, serial FC spin)
// + ONLY two pure compute-side grafts (both HW-verified correct in R8):
//   - make_afrag hi/lo split via v_perm_b32 (1 op instead of 6 per word).
//   - P partials stride PR=20: write banks 2 lanes/bank (free) vs 4-way.
// R7/R8 lesson (both blew up identically: WRITE 134MB->40GB, dur 12-28x,
// never settling across graph replays): the combined fixN retry floods the
// fabric with 16 agent-loads per spin iteration; serialized fix4 is an
// accidental rate-limiter that lets producers win and lockstep re-form.
// Do NOT widen the retry loop without real backoff.

constexpr int Bb = 64, Tt = 512, DIN = 128, Hh = 512;
constexpr int BH = Bb * Hh;
constexpr int S0 = 644;    // LDS A-row stride (u32), layer0: 128 x + 512 h + 4 pad
constexpr int S1 = 1028;   // layer1: 512 h0 + 512 h1 + 4 pad
constexpr int PR = 20;     // partials row stride: conflict-free (2-way) writes

typedef float  f32x4  __attribute__((ext_vector_type(4)));
typedef short  bf16x8 __attribute__((ext_vector_type(8)));
typedef int    i32x4  __attribute__((ext_vector_type(4)));
typedef unsigned long long u64;

#define MFMA16 __builtin_amdgcn_mfma_f32_16x16x32_bf16

__device__ __forceinline__ unsigned rne_bf16(unsigned xb){
    return (xb + 0x7FFFu + ((xb >> 16) & 1u)) >> 16;
}
__device__ __forceinline__ unsigned pack_split(float x){
    unsigned hb = rne_bf16(__float_as_uint(x));
    float hf = __uint_as_float(hb << 16);
    unsigned lb = rne_bf16(__float_as_uint(x - hf));
    return (hb << 16) | lb;
}
__device__ __forceinline__ float unpack_f32(unsigned u){
    return __uint_as_float(u & 0xFFFF0000u) + __uint_as_float(u << 16);
}

union FragU { unsigned w[4]; bf16x8 v; };

__device__ __forceinline__ void make_wfrag(const float* p, bf16x8& wh, bf16x8& wl){
    FragU hi, lo;
#pragma unroll
    for (int i = 0; i < 4; ++i){
        unsigned pa = pack_split(p[2*i]), pb = pack_split(p[2*i+1]);
        hi.w[i] = (pa >> 16) | (pb & 0xFFFF0000u);
        lo.w[i] = (pa & 0xFFFFu) | (pb << 16);
    }
    wh = hi.v; wl = lo.v;
}
// hi word = [b3,b2,a3,a2], lo word = [b1,b0,a1,a0] -- one v_perm_b32 each.
// (HW-verified correct in R8, absmax=0.)
__device__ __forceinline__ void make_afrag(const unsigned* u, bf16x8& ah, bf16x8& al){
    FragU hi, lo;
#pragma unroll
    for (int i = 0; i < 4; ++i){
        unsigned a = u[2*i], b = u[2*i+1];
        hi.w[i] = __builtin_amdgcn_perm(b, a, 0x07060302u);
        lo.w[i] = __builtin_amdgcn_perm(b, a, 0x05040100u);
    }
    ah = hi.v; al = lo.v;
}

__device__ __forceinline__ u64 ald64(const u64* p){
    return __hip_atomic_load(p, __ATOMIC_RELAXED, __HIP_MEMORY_SCOPE_AGENT);
}
__device__ __forceinline__ void ast64(u64* p, u64 v){
    __hip_atomic_store(p, v, __ATOMIC_RELAXED, __HIP_MEMORY_SCOPE_AGENT);
}

// all 4 words must have bit0 == tag
__device__ __forceinline__ bool bad4(const i32x4& v, unsigned tag){
    unsigned x = ((unsigned)v[0] ^ tag) | ((unsigned)v[1] ^ tag)
               | ((unsigned)v[2] ^ tag) | ((unsigned)v[3] ^ tag);
    return (x & 1u) != 0u;
}
// retry path: bypass stale cached line via IF (agent) loads.
// SERIALIZED on purpose -- acts as a fabric rate-limiter (see header).
__device__ __forceinline__ void fix4(const unsigned* p, unsigned tag, i32x4& v){
    if (bad4(v, tag)){
        for (;;){
            u64 a = ald64((const u64*)p);
            u64 b = ald64((const u64*)p + 1);
            v[0] = (int)(unsigned)a; v[1] = (int)(unsigned)(a >> 32);
            v[2] = (int)(unsigned)b; v[3] = (int)(unsigned)(b >> 32);
            if (!bad4(v, tag)) break;
            __builtin_amdgcn_s_sleep(1);
        }
    }
}

template<bool BIG>
__global__ __launch_bounds__(512, 1) void gru_main(
    const float* __restrict__ X,
    const float* __restrict__ Wih0, const float* __restrict__ Whh0,
    const float* __restrict__ bih0, const float* __restrict__ bhh0,
    const float* __restrict__ Wih1, const float* __restrict__ Whh1,
    const float* __restrict__ bih1, const float* __restrict__ bhh1,
    const float* __restrict__ fcW, const float* __restrict__ fcb,
    float* __restrict__ out,
    unsigned* hseq0, unsigned* hseq1)
{
    // Kill stale clean L1/L2 lines left from the previous graph replay.
    __builtin_amdgcn_fence(__ATOMIC_ACQUIRE, "agent");

    __shared__ unsigned Alds[16 * S1];
    __shared__ float P[8][3][16 * PR];
    __shared__ unsigned hout[256];

    const int tid  = threadIdx.x;
    const int lane = tid & 63;
    const int w    = tid >> 6;
    const bool isL1 = blockIdx.x >= 128;
    const int lb = isL1 ? (int)blockIdx.x - 128 : (int)blockIdx.x;
    const int m  = lb >> 5;                // batch tile 0..3
    const int cb = lb & 31;                // col-block 0..31
    const int c0 = cb * 16;
    const int STR  = isL1 ? S1 : S0;
    const int HOFF = isL1 ? 512 : 128;

    const bool active = isL1 || (w < 5);   // layer0 K=640 -> 5 waves x 128

    // ---- register-resident weight fragments (hi/lo split-bf16) ----
    bf16x8 whi[4][3], wlo[4][3];
    if (active){
        const int n = lane & 15;
#pragma unroll
        for (int ks = 0; ks < 4; ++ks){
            int kq = w * 128 + ks * 32 + (lane >> 4) * 8;
            const float* src; long kloc, rowlen;
            if (isL1){
                if (kq < 512){ src = Wih1; kloc = kq; } else { src = Whh1; kloc = kq - 512; }
                rowlen = 512;
            } else {
                if (kq < 128){ src = Wih0; kloc = kq; rowlen = 128; }
                else         { src = Whh0; kloc = kq - 128; rowlen = 512; }
            }
#pragma unroll
            for (int g = 0; g < 3; ++g){
                long row = (long)g * Hh + c0 + n;
                make_wfrag(src + row * rowlen + kloc, whi[ks][g], wlo[ks][g]);
            }
        }
    }
    // ---- biases for epilogue ----
    float Br = 0.f, Bz = 0.f, Bin = 0.f, Bhn = 0.f;
    if (tid < 256){
        int c = c0 + (tid & 15);
        const float* bi = isL1 ? bih1 : bih0;
        const float* bh = isL1 ? bhh1 : bhh0;
        Br  = bi[c] + bh[c];
        Bz  = bi[Hh + c] + bh[Hh + c];
        Bin = bi[2*Hh + c];
        Bhn = bh[2*Hh + c];
    }

    for (int t = 0; t < Tt; ++t){
        // ---- staging: all 8 waves, speculative loads + validity fix-up ----
        if (isL1){
            const unsigned* s0 = hseq0 + ((long)t * Bb + m*16) * (long)Hh;
            long r1 = BIG ? (long)(t-1) * BH : (long)((t-1) & 1) * BH;
            const unsigned* s1 = hseq1 + r1 + (long)(m*16) * Hh;
            unsigned tag1 = BIG ? 1u : (1u - (((unsigned)(t-1) >> 1) & 1u));
            const unsigned* a0[4]; const unsigned* a1[4];
            i32x4 v0[4], v1[4];
#pragma unroll
            for (int it = 0; it < 4; ++it){
                int j = it*512 + tid; int row = j >> 7, col = (j & 127) * 4;
                a0[it] = s0 + (long)row * Hh + col;
                v0[it] = *(const i32x4*)a0[it];
            }
            if (t > 0){
#pragma unroll
                for (int it = 0; it < 4; ++it){
                    int j = it*512 + tid; int row = j >> 7, col = (j & 127) * 4;
                    a1[it] = s1 + (long)row * Hh + col;
                    v1[it] = *(const i32x4*)a1[it];
                }
            }
#pragma unroll
            for (int it = 0; it < 4; ++it) fix4(a0[it], 1u, v0[it]);
            if (t > 0){
#pragma unroll
                for (int it = 0; it < 4; ++it) fix4(a1[it], tag1, v1[it]);
            } else {
#pragma unroll
                for (int it = 0; it < 4; ++it) v1[it] = i32x4{0,0,0,0};
            }
#pragma unroll
            for (int it = 0; it < 4; ++it){
                int j = it*512 + tid; int row = j >> 7, col = (j & 127) * 4;
                *(i32x4*)(Alds + row * S1 + col) = v0[it];
                *(i32x4*)(Alds + row * S1 + 512 + col) = v1[it];
            }
        } else {
            // X[t] fp32 (cached input) -> pack on the fly
            {
                int row = tid >> 5, c4 = (tid & 31) * 4;
                f32x4 xv = *(const f32x4*)(X + ((long)(m*16 + row) * Tt + t) * DIN + c4);
                i32x4 pv;
                pv[0] = (int)pack_split(xv[0]);
                pv[1] = (int)pack_split(xv[1]);
                pv[2] = (int)pack_split(xv[2]);
                pv[3] = (int)pack_split(xv[3]);
                *(i32x4*)(Alds + row * S0 + c4) = pv;
            }
            if (t > 0){
                const unsigned* s0 = hseq0 + ((long)(t-1) * Bb + m*16) * (long)Hh;
                const unsigned* a0[4]; i32x4 v0[4];
#pragma unroll
                for (int it = 0; it < 4; ++it){
                    int j = it*512 + tid; int row = j >> 7, col = (j & 127) * 4;
                    a0[it] = s0 + (long)row * Hh + col;
                    v0[it] = *(const i32x4*)a0[it];
                }
#pragma unroll
                for (int it = 0; it < 4; ++it) fix4(a0[it], 1u, v0[it]);
#pragma unroll
                for (int it = 0; it < 4; ++it){
                    int j = it*512 + tid; int row = j >> 7, col = (j & 127) * 4;
                    *(i32x4*)(Alds + row * S0 + 128 + col) = v0[it];
                }
            } else {
#pragma unroll
                for (int it = 0; it < 8; ++it){
                    int j = it*512 + tid;
                    *(u64*)(Alds + (j >> 8) * S0 + 128 + (j & 255) * 2) = 0ULL;
                }
            }
        }
        __syncthreads();

        // ---- MFMA: this wave's K-slice, tiles {r, z, nx-or-nh} ----
        if (active){
            f32x4 a0 = {0.f,0.f,0.f,0.f}, a1 = a0, a2 = a0;
            const unsigned* arow = Alds + (lane & 15) * STR + w * 128 + (lane >> 4) * 8;
#pragma unroll
            for (int ks = 0; ks < 4; ++ks){
                unsigned uu[8];
                *(i32x4*)&uu[0] = *(const i32x4*)(arow + ks*32);
                *(i32x4*)&uu[4] = *(const i32x4*)(arow + ks*32 + 4);
                bf16x8 ah, al; make_afrag(uu, ah, al);
                a0 = MFMA16(ah, whi[ks][0], a0, 0,0,0);
                a0 = MFMA16(ah, wlo[ks][0], a0, 0,0,0);
                a0 = MFMA16(al, whi[ks][0], a0, 0,0,0);
                a1 = MFMA16(ah, whi[ks][1], a1, 0,0,0);
                a1 = MFMA16(ah, wlo[ks][1], a1, 0,0,0);
                a1 = MFMA16(al, whi[ks][1], a1, 0,0,0);
                a2 = MFMA16(ah, whi[ks][2], a2, 0,0,0);
                a2 = MFMA16(ah, wlo[ks][2], a2, 0,0,0);
                a2 = MFMA16(al, whi[ks][2], a2, 0,0,0);
            }
            int q = lane >> 4, n = lane & 15;
#pragma unroll
            for (int r4 = 0; r4 < 4; ++r4){
                int idx = (q*4 + r4)*PR + n;
                P[w][0][idx] = a0[r4];
                P[w][1][idx] = a1[r4];
                P[w][2][idx] = a2[r4];
            }
        }
        __syncthreads();

        // ---- reduce partials + gates -> tagged packed h into LDS ----
        unsigned wtag = isL1 ? (BIG ? 1u : (1u - (((unsigned)t >> 1) & 1u))) : 1u;
        if (tid < 256){
            int bm = tid >> 4, n = tid & 15;
            int idx = bm * PR + n;
            float sr, sz, snx, snh;
            if (isL1){
                sr  = P[0][0][idx]+P[1][0][idx]+P[2][0][idx]+P[3][0][idx]
                    + P[4][0][idx]+P[5][0][idx]+P[6][0][idx]+P[7][0][idx];
                sz  = P[0][1][idx]+P[1][1][idx]+P[2][1][idx]+P[3][1][idx]
                    + P[4][1][idx]+P[5][1][idx]+P[6][1][idx]+P[7][1][idx];
                snx = P[0][2][idx]+P[1][2][idx]+P[2][2][idx]+P[3][2][idx];
                snh = P[4][2][idx]+P[5][2][idx]+P[6][2][idx]+P[7][2][idx];
            } else {
                sr  = P[0][0][idx]+P[1][0][idx]+P[2][0][idx]+P[3][0][idx]+P[4][0][idx];
                sz  = P[0][1][idx]+P[1][1][idx]+P[2][1][idx]+P[3][1][idx]+P[4][1][idx];
                snx = P[0][2][idx];
                snh = P[1][2][idx]+P[2][2][idx]+P[3][2][idx]+P[4][2][idx];
            }
            float r  = 1.f/(1.f + __expf(-(sr + Br)));
            float z  = 1.f/(1.f + __expf(-(sz + Bz)));
            float ee = __expf(2.f*(snx + Bin + r*(snh + Bhn)));
            float nn = 1.f - 2.f/(ee + 1.f);
            float hp = unpack_f32(Alds[bm*STR + HOFF + c0 + n]);
            float hnew = (1.f - z)*nn + z*hp;
            hout[tid] = (pack_split(hnew) & ~1u) | wtag;   // hout[bm*16 + n]
        }
        __syncthreads();

        // ---- agent u64 stores; NO ack wait, NO flag — sail into t+1 ----
        if (tid < 128){
            int bm = tid >> 3, k = (tid & 7) * 2;
            u64 v = (u64)hout[bm*16 + k] | ((u64)hout[bm*16 + k + 1] << 32);
            unsigned* base = isL1
                ? hseq1 + (BIG ? (long)t * BH : (long)(t & 1) * BH)
                : hseq0 + (long)t * BH;
            ast64((u64*)(base + (long)(m*16 + bm) * Hh + c0 + k), v);
        }
    }

    // ---- FC epilogue: one layer1 block per m, validated reads ----
    if (isL1 && cb == 31){
        unsigned ftag = BIG ? 1u : (1u - (((unsigned)(Tt-1) >> 1) & 1u));
        const unsigned* hb = hseq1 + (BIG ? (long)(Tt-1) * BH : (long)((Tt-1) & 1) * BH);
        int half = lane >> 5, l5 = lane & 31;
        int b = m*16 + w*2 + half;
        const u64* hrow = (const u64*)(hb + (long)b * Hh);
        float p = 0.f;
#pragma unroll
        for (int i = 0; i < 8; ++i){
            int k = l5 + 32*i;
            u64 v = ald64(hrow + k);
            while (((((unsigned)v ^ ftag) | ((unsigned)(v >> 32) ^ ftag)) & 1u) != 0u){
                __builtin_amdgcn_s_sleep(1);
                v = ald64(hrow + k);
            }
            p += unpack_f32((unsigned)v) * fcW[2*k]
               + unpack_f32((unsigned)(v >> 32)) * fcW[2*k+1];
        }
#pragma unroll
        for (int off = 16; off > 0; off >>= 1) p += __shfl_xor(p, off);
        if (l5 == 0) out[b] = p + fcb[0];
    }
}

extern "C" void kernel_launch(void* const* d_in, const int* in_sizes, int n_in,
                              void* d_out, int out_size, void* d_ws, size_t ws_size,
                              hipStream_t stream) {
    const float* X    = (const float*)d_in[0];
    const float* Wih0 = (const float*)d_in[1];
    const float* Whh0 = (const float*)d_in[2];
    const float* bih0 = (const float*)d_in[3];
    const float* bhh0 = (const float*)d_in[4];
    const float* Wih1 = (const float*)d_in[5];
    const float* Whh1 = (const float*)d_in[6];
    const float* bih1 = (const float*)d_in[7];
    const float* bhh1 = (const float*)d_in[8];
    const float* fcW  = (const float*)d_in[9];
    const float* fcb  = (const float*)d_in[10];
    float* out = (float*)d_out;

    // ws: hseq0 64 MiB | hseq1 64 MiB (BIG) or 256 KiB ring. No flags, no memset:
    // harness poisons ws to 0xAA (bit0=0 = invalid) before every launch.
    unsigned* hseq0 = (unsigned*)d_ws;
    unsigned* hseq1 = hseq0 + (long)Tt * BH;
    size_t need_big = (size_t)2 * Tt * BH * 4;    // 128 MiB
    bool big = ws_size >= need_big;

    if (big)
        gru_main<true><<<256, 512, 0, stream>>>(X, Wih0, Whh0, bih0, bhh0,
                                                Wih1, Whh1, bih1, bhh1, fcW, fcb,
                                                out, hseq0, hseq1);
    else
        gru_main<false><<<256, 512, 0, stream>>>(X, Wih0, Whh0, bih0, bhh0,
                                                 Wih1, Whh1, bih1, bhh1, fcW, fcb,
                                                 out, hseq0, hseq1);
}